// Round 1
// baseline (608.776 us; speedup 1.0000x reference)
//
#include <hip/hip_runtime.h>
#include <stdint.h>

#define BQ 4
#define NQ 2048
#define DQ 512
#define YQ 8921
#define YTILES 279           // ceil(YQ/32)
#define NCHUNK 64            // NQ/32
#define NBLK (YTILES * BQ)   // 1116
#define WBYTES 98304         // 96 rows * 1024 B
#define XOFF 98304
#define XBUFSZ 32768
#define L2E 1.44269504088896340736f

typedef __attribute__((ext_vector_type(8))) short bf16x8;
typedef __attribute__((ext_vector_type(4))) float f32x4;
typedef __attribute__((ext_vector_type(4))) int i32x4;

__device__ inline short f2bf(float f) {
  unsigned u = __float_as_uint(f);
  u += 0x7fffu + ((u >> 16) & 1u);   // RTNE
  return (short)(u >> 16);
}

// ---- pre-pass: gx[b,n] = x[b,n,:] . gate_w  (f32), optional x -> bf16 linear copy ----
template<bool STOREX>
__global__ __launch_bounds__(256) void prep_kernel(const float* __restrict__ x,
                                                   const float* __restrict__ gate_w,
                                                   char* __restrict__ ws_x,
                                                   float* __restrict__ gx) {
  int rid = blockIdx.x * 4 + (threadIdx.x >> 6);   // (b*N + n), rid < 8192
  int lane = threadIdx.x & 63;
  const float* src = x + (size_t)rid * DQ + lane * 8;
  float4 v0 = *(const float4*)src;
  float4 v1 = *(const float4*)(src + 4);
  const float* gwp = gate_w + lane * 8;
  float s = v0.x * gwp[0] + v0.y * gwp[1] + v0.z * gwp[2] + v0.w * gwp[3]
          + v1.x * gwp[4] + v1.y * gwp[5] + v1.z * gwp[6] + v1.w * gwp[7];
#pragma unroll
  for (int d = 1; d < 64; d <<= 1) s += __shfl_xor(s, d);
  if (lane == 0) gx[rid] = s;
  if constexpr (STOREX) {
    bf16x8 h;
    h[0] = f2bf(v0.x); h[1] = f2bf(v0.y); h[2] = f2bf(v0.z); h[3] = f2bf(v0.w);
    h[4] = f2bf(v1.x); h[5] = f2bf(v1.y); h[6] = f2bf(v1.z); h[7] = f2bf(v1.w);
    *(bf16x8*)(ws_x + (size_t)rid * 1024 + lane * 16) = h;
  }
}

// ---- fused: 3 matmuls + dual online softmax + epilogue ----
template<bool PRECONV>
__global__ __launch_bounds__(512, 1) void fused_kernel(
    const float* __restrict__ x, const float* __restrict__ Uw,
    const float* __restrict__ Gw, const float* __restrict__ Fw,
    const float* __restrict__ fb, const float* __restrict__ gate_b,
    const float* __restrict__ yflow, const float* __restrict__ target,
    const char* __restrict__ ws_x, const float* __restrict__ gx,
    float* __restrict__ out_y, float* __restrict__ loss_part) {
  extern __shared__ char smem[];
  const int tid = threadIdx.x;
  const int l = tid & 63;
  const int w = tid >> 6;
  const int ybase = blockIdx.x * 32;
  const int b = blockIdx.y;

  // ---- stage W: rows 0-31 = U, 32-63 = Ug, 64-95 = F; bf16, XOR-swizzled ----
#pragma unroll
  for (int i = 0; i < 12; ++i) {
    int o = (i * 512 + tid) * 16;     // byte offset in W area; each wave = one 1KB row
    int row = o >> 10;                // 0..95
    int mat = row >> 5;
    int y = ybase + (row & 31);
    int fo = (o & 1023) >> 1;         // element offset in row
    float4 a0 = make_float4(0.f, 0.f, 0.f, 0.f), a1 = a0;
    if (y < YQ) {
      const float* sw = (mat == 0 ? Uw : (mat == 1 ? Gw : Fw)) + (size_t)y * DQ + fo;
      a0 = *(const float4*)sw;
      a1 = *(const float4*)(sw + 4);
    }
    bf16x8 h;
    h[0] = f2bf(a0.x); h[1] = f2bf(a0.y); h[2] = f2bf(a0.z); h[3] = f2bf(a0.w);
    h[4] = f2bf(a1.x); h[5] = f2bf(a1.y); h[6] = f2bf(a1.z); h[7] = f2bf(a1.w);
    *(bf16x8*)(smem + (o ^ ((row & 7) << 4))) = h;
  }

  // ---- stage x chunk 0 into buf0 ----
#pragma unroll
  for (int k = 0; k < 4; ++k) {
    int o = (k * 512 + tid) * 16;
    int r = o >> 10;
    if constexpr (PRECONV) {
      i32x4 v = *(const i32x4*)(ws_x + (((size_t)(b * NQ)) << 10) + o);
      *(i32x4*)(smem + XOFF + (o ^ ((r & 7) << 4))) = v;
    } else {
      const float* xs = x + (((size_t)(b * NQ)) << 9) + (o >> 1);
      float4 q0 = *(const float4*)xs, q1 = *(const float4*)(xs + 4);
      bf16x8 h;
      h[0] = f2bf(q0.x); h[1] = f2bf(q0.y); h[2] = f2bf(q0.z); h[3] = f2bf(q0.w);
      h[4] = f2bf(q1.x); h[5] = f2bf(q1.y); h[6] = f2bf(q1.z); h[7] = f2bf(q1.w);
      *(bf16x8*)(smem + XOFF + (o ^ ((r & 7) << 4))) = h;
    }
  }
  __syncthreads();

  const int lr = l & 15, lg4 = l >> 4;
  const int swz = (l & 7) << 4;
  const int ilow = (lg4 << 4) ^ swz;
  const bool mainw = (w < 4);
  const int wu = mainw ? w : (w - 4);
  const int ys = wu >> 1, nc = wu & 1;
  const int wrow = mainw ? (ys * 16) : (32 + ys * 16);
  const char* uB = smem + ((size_t)(wrow + lr) << 10);
  const char* fB = smem + ((size_t)(64 + ys * 16 + lr) << 10);

  float m_r = -INFINITY, l_r = 0.f, a_r = 0.f;

  for (int c = 0; c < NCHUNK; ++c) {
    // issue next-chunk global loads early (latency hides under MFMA)
    i32x4 nv[4];
    float4 nf0[4], nf1[4];
    if (c < NCHUNK - 1) {
#pragma unroll
      for (int k = 0; k < 4; ++k) {
        int o = (k * 512 + tid) * 16;
        if constexpr (PRECONV) {
          nv[k] = *(const i32x4*)(ws_x + (((size_t)(b * NQ + (c + 1) * 32)) << 10) + o);
        } else {
          const float* xs = x + (((size_t)(b * NQ + (c + 1) * 32)) << 9) + (o >> 1);
          nf0[k] = *(const float4*)xs;
          nf1[k] = *(const float4*)(xs + 4);
        }
      }
    }
    float gxv[4];
    if (!mainw) {
#pragma unroll
      for (int r = 0; r < 4; ++r) gxv[r] = gx[b * NQ + c * 32 + nc * 16 + lg4 * 4 + r];
    }

    const char* ab = smem + XOFF + (size_t)((c & 1) * XBUFSZ) + ((size_t)(nc * 16 + lr) << 10);
    f32x4 s1 = {0.f, 0.f, 0.f, 0.f};
    f32x4 s2 = {0.f, 0.f, 0.f, 0.f};
    if (mainw) {
#pragma unroll
      for (int k = 0; k < 16; ++k) {
        int io = (k << 6) ^ ilow;
        bf16x8 a  = *(const bf16x8*)(ab + io);
        bf16x8 bu = *(const bf16x8*)(uB + io);
        bf16x8 bf_ = *(const bf16x8*)(fB + io);
        s1 = __builtin_amdgcn_mfma_f32_16x16x32_bf16(a, bu, s1, 0, 0, 0);
        s2 = __builtin_amdgcn_mfma_f32_16x16x32_bf16(a, bf_, s2, 0, 0, 0);
      }
    } else {
#pragma unroll
      for (int k = 0; k < 16; ++k) {
        int io = (k << 6) ^ ilow;
        bf16x8 a  = *(const bf16x8*)(ab + io);
        bf16x8 bg = *(const bf16x8*)(uB + io);
        s1 = __builtin_amdgcn_mfma_f32_16x16x32_bf16(a, bg, s1, 0, 0, 0);
      }
    }

    // online softmax over this wave's 16 n-rows (cols = y, 4 rows/lane + xor16/32)
    float pm = fmaxf(fmaxf(s1[0], s1[1]), fmaxf(s1[2], s1[3]));
    pm = fmaxf(pm, __shfl_xor(pm, 16));
    pm = fmaxf(pm, __shfl_xor(pm, 32));
    float mn = fmaxf(m_r, pm);
    float sc = exp2f((m_r - mn) * L2E);
    float es = 0.f, ea = 0.f;
#pragma unroll
    for (int r = 0; r < 4; ++r) {
      float e = exp2f((s1[r] - mn) * L2E);
      es += e;
      ea += e * (mainw ? s2[r] : gxv[r]);
    }
    es += __shfl_xor(es, 16); es += __shfl_xor(es, 32);
    ea += __shfl_xor(ea, 16); ea += __shfl_xor(ea, 32);
    l_r = l_r * sc + es;
    a_r = a_r * sc + ea;
    m_r = mn;

    // write next chunk to the other buffer (its readers finished a barrier ago)
    if (c < NCHUNK - 1) {
      char* xb2 = smem + XOFF + (size_t)(((c + 1) & 1) * XBUFSZ);
#pragma unroll
      for (int k = 0; k < 4; ++k) {
        int o = (k * 512 + tid) * 16;
        int r2 = o >> 10;
        if constexpr (PRECONV) {
          *(i32x4*)(xb2 + (o ^ ((r2 & 7) << 4))) = nv[k];
        } else {
          bf16x8 h;
          h[0] = f2bf(nf0[k].x); h[1] = f2bf(nf0[k].y); h[2] = f2bf(nf0[k].z); h[3] = f2bf(nf0[k].w);
          h[4] = f2bf(nf1[k].x); h[5] = f2bf(nf1[k].y); h[6] = f2bf(nf1[k].z); h[7] = f2bf(nf1[k].w);
          *(bf16x8*)(xb2 + (o ^ ((r2 & 7) << 4))) = h;
        }
      }
    }
    __syncthreads();
  }

  // ---- merge per-wave partial softmax states ----
  float* M = (float*)(smem + XOFF);
  {
    int branch = mainw ? 0 : 1;
    int idx = ((branch * 2 + ys) * 2 + nc) * 16 + lr;
    if (lg4 == 0) { M[idx] = m_r; M[128 + idx] = l_r; M[256 + idx] = a_r; }
  }
  __syncthreads();

  float lt = 0.f;
  if (tid < 32) {
    int yy = ybase + tid;
    int yl = tid & 15, yss = tid >> 4;
    int i0 = ((0 * 2 + yss) * 2 + 0) * 16 + yl, i1 = i0 + 16;
    float m0 = M[i0], l0 = M[128 + i0], a0 = M[256 + i0];
    float m1 = M[i1], l1 = M[128 + i1], a1 = M[256 + i1];
    float mm = fmaxf(m0, m1);
    float e0 = exp2f((m0 - mm) * L2E), e1 = exp2f((m1 - mm) * L2E);
    float fval = (a0 * e0 + a1 * e1) / (l0 * e0 + l1 * e1);
    int j0 = ((1 * 2 + yss) * 2 + 0) * 16 + yl, j1 = j0 + 16;
    float gm0 = M[j0], gl0 = M[128 + j0], ga0 = M[256 + j0];
    float gm1 = M[j1], gl1 = M[128 + j1], ga1 = M[256 + j1];
    float gmm = fmaxf(gm0, gm1);
    float g0 = exp2f((gm0 - gmm) * L2E), g1 = exp2f((gm1 - gmm) * L2E);
    float gate = tanhf((ga0 * g0 + ga1 * g1) / (gl0 * g0 + gl1 * g1) + gate_b[0]);
    if (yy < YQ) {
      float yv = fval + fb[yy] + yflow[b * YQ + yy] * gate;
      out_y[b * YQ + yy] = yv;
      float t = target[b * YQ + yy];
      lt = fmaxf(yv, 0.f) + log1pf(__expf(-fabsf(yv))) - yv * t;
    }
  }
  if (w == 0) {
#pragma unroll
    for (int d = 1; d < 64; d <<= 1) lt += __shfl_xor(lt, d);
    if (tid == 0) loss_part[blockIdx.y * YTILES + blockIdx.x] = lt;
  }
}

__global__ __launch_bounds__(256) void loss_kernel(const float* __restrict__ lp,
                                                   float* __restrict__ out) {
  __shared__ float sb[256];
  float s = 0.f;
  for (int i = threadIdx.x; i < NBLK; i += 256) s += lp[i];
  sb[threadIdx.x] = s;
  __syncthreads();
  for (int st = 128; st > 0; st >>= 1) {
    if (threadIdx.x < st) sb[threadIdx.x] += sb[threadIdx.x + st];
    __syncthreads();
  }
  if (threadIdx.x == 0) out[BQ * YQ] = sb[0] / (float)(BQ * YQ);
}

extern "C" void kernel_launch(void* const* d_in, const int* in_sizes, int n_in,
                              void* d_out, int out_size, void* d_ws, size_t ws_size,
                              hipStream_t stream) {
  const float* x      = (const float*)d_in[0];
  const float* target = (const float*)d_in[1];
  const float* yflow  = (const float*)d_in[2];
  const float* Uw     = (const float*)d_in[3];
  const float* Gw     = (const float*)d_in[4];
  const float* Fw     = (const float*)d_in[5];
  const float* fb     = (const float*)d_in[6];
  const float* gw     = (const float*)d_in[7];
  const float* gb     = (const float*)d_in[8];
  float* out = (float*)d_out;
  char* ws = (char*)d_ws;

  const size_t xbytes = (size_t)BQ * NQ * DQ * 2;                 // 8 MB
  const size_t gxbytes = (size_t)BQ * NQ * 4;
  const size_t need_fast = xbytes + gxbytes + (size_t)NBLK * 4;
  const bool fast = ws_size >= need_fast;

  char* ws_x; float* gxp; float* lp;
  if (fast) {
    ws_x = ws;
    gxp = (float*)(ws + xbytes);
    lp  = (float*)(ws + xbytes + gxbytes);
  } else {
    ws_x = nullptr;
    gxp = (float*)ws;
    lp  = (float*)(ws + gxbytes);
  }

  (void)hipFuncSetAttribute(reinterpret_cast<const void*>(&fused_kernel<true>),
                            hipFuncAttributeMaxDynamicSharedMemorySize, 163840);
  (void)hipFuncSetAttribute(reinterpret_cast<const void*>(&fused_kernel<false>),
                            hipFuncAttributeMaxDynamicSharedMemorySize, 163840);

  if (fast) prep_kernel<true ><<<dim3(BQ * NQ / 4), 256, 0, stream>>>(x, gw, ws_x, gxp);
  else      prep_kernel<false><<<dim3(BQ * NQ / 4), 256, 0, stream>>>(x, gw, ws_x, gxp);

  dim3 grid(YTILES, BQ);
  if (fast)
    fused_kernel<true ><<<grid, 512, 163840, stream>>>(x, Uw, Gw, Fw, fb, gb, yflow,
                                                       target, ws_x, gxp, out, lp);
  else
    fused_kernel<false><<<grid, 512, 163840, stream>>>(x, Uw, Gw, Fw, fb, gb, yflow,
                                                       target, ws_x, gxp, out, lp);

  loss_kernel<<<1, 256, 0, stream>>>(lp, out);
}

// Round 2
// 384.751 us; speedup vs baseline: 1.5823x; 1.5823x over previous
//
#include <hip/hip_runtime.h>
#include <stdint.h>

#define BQ 4
#define NQ 2048
#define DQ 512
#define YQ 8921
#define YGRP 140                 // ceil(8921/64) y-groups of 64
#define NBLOCKS (YGRP * BQ)      // 560
#define NCH 64                   // n-chunks of 32 rows
#define CHB 32768                // chunk bytes: 32 rows * 1KB
#define L2E 1.44269504088896340736f

typedef __attribute__((ext_vector_type(8))) short bf16x8;
typedef __attribute__((ext_vector_type(4))) float f32x4;

__device__ inline short f2bf(float f) {
  unsigned u = __float_as_uint(f);
  u += 0x7fffu + ((u >> 16) & 1u);   // RTNE
  return (short)(u >> 16);
}

__device__ inline bf16x8 pack8(float4 a, float4 b) {
  bf16x8 h;
  h[0] = f2bf(a.x); h[1] = f2bf(a.y); h[2] = f2bf(a.z); h[3] = f2bf(a.w);
  h[4] = f2bf(b.x); h[5] = f2bf(b.y); h[6] = f2bf(b.z); h[7] = f2bf(b.w);
  return h;
}

__device__ inline void gl_lds16(const void* g, void* l) {
  __builtin_amdgcn_global_load_lds((const __attribute__((address_space(1))) void*)g,
                                   (__attribute__((address_space(3))) void*)l, 16, 0, 0);
}

// ---- prep 1: gx[b,n] = x[b,n,:].gate_w ; optionally x -> bf16 (row-major, linear) ----
template<bool STOREX>
__global__ __launch_bounds__(256) void prep_x(const float* __restrict__ x,
                                              const float* __restrict__ gate_w,
                                              char* __restrict__ ws_x,
                                              float* __restrict__ gx) {
  int rid = blockIdx.x * 4 + (threadIdx.x >> 6);   // b*N+n < 8192
  int lane = threadIdx.x & 63;
  const float* src = x + (size_t)rid * DQ + lane * 8;
  float4 v0 = *(const float4*)src;
  float4 v1 = *(const float4*)(src + 4);
  const float* gwp = gate_w + lane * 8;
  float s = v0.x * gwp[0] + v0.y * gwp[1] + v0.z * gwp[2] + v0.w * gwp[3]
          + v1.x * gwp[4] + v1.y * gwp[5] + v1.z * gwp[6] + v1.w * gwp[7];
#pragma unroll
  for (int d = 1; d < 64; d <<= 1) s += __shfl_xor(s, d);
  if (lane == 0) gx[rid] = s;
  if constexpr (STOREX)
    *(bf16x8*)(ws_x + (size_t)rid * 1024 + lane * 16) = pack8(v0, v1);
}

// ---- prep 2: W (U,Ug,F) f32 -> bf16 into ws_w [3][YQ][512] ----
__global__ __launch_bounds__(256) void prep_w(const float* __restrict__ Uw,
                                              const float* __restrict__ Gw,
                                              const float* __restrict__ Fw,
                                              char* __restrict__ ws_w) {
  int rid = blockIdx.x * 4 + (threadIdx.x >> 6);
  if (rid >= 3 * YQ) return;
  int lane = threadIdx.x & 63;
  int mat = rid / YQ, y = rid % YQ;
  const float* src = (mat == 0 ? Uw : (mat == 1 ? Gw : Fw)) + (size_t)y * DQ + lane * 8;
  float4 v0 = *(const float4*)src;
  float4 v1 = *(const float4*)(src + 4);
  *(bf16x8*)(ws_w + (size_t)rid * 1024 + lane * 16) = pack8(v0, v1);
}

// ---- fused: W-in-registers, x streamed through LDS in frag-linear layout ----
// block = 256 thr = 4 waves; wave w owns y-tile [yg*64 + w*16, +16), all 3 branches, full n.
// LDS x-chunk layout: [tile2][kstep][lane]*16B  -> frag read is contiguous 1KB.
template<bool FULL>
__global__ __launch_bounds__(256, 2) void fused_kernel(
    const float* __restrict__ x, const char* __restrict__ ws_x,
    const char* __restrict__ ws_w,
    const float* __restrict__ Uw, const float* __restrict__ Gw,
    const float* __restrict__ Fw, const float* __restrict__ gx,
    const float* __restrict__ fb, const float* __restrict__ gate_b,
    const float* __restrict__ yflow, const float* __restrict__ target,
    float* __restrict__ out_y, float* __restrict__ loss_part) {
  extern __shared__ char smem[];
  const int tid = threadIdx.x, l = tid & 63, w = tid >> 6;
  const int lr = l & 15, lg4 = l >> 4;
  // XCD-chunked bijective swizzle: 560 = 8*70
  int wg = (blockIdx.x & 7) * (NBLOCKS / 8) + (blockIdx.x >> 3);
  const int b = wg / YGRP, yg = wg % YGRP;
  const int ybase = yg * 64 + w * 16;

  // ---- W fragments into registers (48 frags = 192 VGPR) ----
  bf16x8 wU[16], wG[16], wF[16];
  {
    int y = ybase + lr; if (y >= YQ) y = YQ - 1;
    if constexpr (FULL) {
      const char* p0 = ws_w + ((size_t)y * DQ + lg4 * 8) * 2;
#pragma unroll
      for (int kk = 0; kk < 16; ++kk) {
        wU[kk] = *(const bf16x8*)(p0 + kk * 64);
        wG[kk] = *(const bf16x8*)(p0 + (size_t)YQ * 1024 + kk * 64);
        wF[kk] = *(const bf16x8*)(p0 + (size_t)YQ * 2048 + kk * 64);
      }
    } else {
      const float* pu = Uw + (size_t)y * DQ + lg4 * 8;
      const float* pg = Gw + (size_t)y * DQ + lg4 * 8;
      const float* pf = Fw + (size_t)y * DQ + lg4 * 8;
#pragma unroll
      for (int kk = 0; kk < 16; ++kk) {
        wU[kk] = pack8(*(const float4*)(pu + kk * 32), *(const float4*)(pu + kk * 32 + 4));
        wG[kk] = pack8(*(const float4*)(pg + kk * 32), *(const float4*)(pg + kk * 32 + 4));
        wF[kk] = pack8(*(const float4*)(pf + kk * 32), *(const float4*)(pf + kk * 32 + 4));
      }
    }
  }

  float mU = -INFINITY, lU = 0.f, aU = 0.f;
  float mG = -INFINITY, lG = 0.f, aG = 0.f;
  const float* gxb = gx + b * NQ;

  if constexpr (FULL) {
    const char* xsrc = ws_x + (((size_t)(b * NQ)) << 10);
    // stage(c, buf): 32 segments of 1KB; wave w does s = w*8+j.
    // segment s = (t2,kk); lane l supplies bytes for slot l*16 -> row=l&15, lg4=l>>4.
    auto stage = [&](int c, int bufi) {
      const char* src = xsrc + ((size_t)c << 15);
      char* lb = smem + bufi * CHB;
#pragma unroll
      for (int j = 0; j < 8; ++j) {
        int s = w * 8 + j, t2 = s >> 4, kk = s & 15;
        gl_lds16(src + (((t2 * 16 + lr)) << 10) + kk * 64 + lg4 * 16,
                 lb + s * 1024);
      }
    };
    stage(0, 0);
    asm volatile("s_waitcnt vmcnt(0)" ::: "memory");
    __syncthreads();

    for (int c = 0; c < NCH; ++c) {
      if (c + 1 < NCH) stage(c + 1, (c + 1) & 1);
      const char* buf = smem + (c & 1) * CHB;
#pragma unroll
      for (int t2 = 0; t2 < 2; ++t2) {
        f32x4 sU = {0.f, 0.f, 0.f, 0.f}, sG = sU, sF = sU;
        const char* ab = buf + t2 * 16384 + l * 16;
#pragma unroll
        for (int kk = 0; kk < 16; ++kk) {
          bf16x8 a = *(const bf16x8*)(ab + kk * 1024);
          sU = __builtin_amdgcn_mfma_f32_16x16x32_bf16(a, wU[kk], sU, 0, 0, 0);
          sG = __builtin_amdgcn_mfma_f32_16x16x32_bf16(a, wG[kk], sG, 0, 0, 0);
          sF = __builtin_amdgcn_mfma_f32_16x16x32_bf16(a, wF[kk], sF, 0, 0, 0);
        }
        float4 gxv = *(const float4*)(gxb + c * 32 + t2 * 16 + lg4 * 4);
        // U branch (values = F scores)
        float pm = fmaxf(fmaxf(sU[0], sU[1]), fmaxf(sU[2], sU[3]));
        pm = fmaxf(pm, __shfl_xor(pm, 16)); pm = fmaxf(pm, __shfl_xor(pm, 32));
        float mn = fmaxf(mU, pm);
        float sc = exp2f((mU - mn) * L2E);
        float es = 0.f, ea = 0.f;
#pragma unroll
        for (int r = 0; r < 4; ++r) {
          float e = exp2f((sU[r] - mn) * L2E);
          es += e; ea += e * sF[r];
        }
        es += __shfl_xor(es, 16); es += __shfl_xor(es, 32);
        ea += __shfl_xor(ea, 16); ea += __shfl_xor(ea, 32);
        lU = lU * sc + es; aU = aU * sc + ea; mU = mn;
        // G branch (values = gx scalars)
        float pg = fmaxf(fmaxf(sG[0], sG[1]), fmaxf(sG[2], sG[3]));
        pg = fmaxf(pg, __shfl_xor(pg, 16)); pg = fmaxf(pg, __shfl_xor(pg, 32));
        float mng = fmaxf(mG, pg);
        float scg = exp2f((mG - mng) * L2E);
        float eg = 0.f, eag = 0.f;
        float gv[4] = {gxv.x, gxv.y, gxv.z, gxv.w};
#pragma unroll
        for (int r = 0; r < 4; ++r) {
          float e = exp2f((sG[r] - mng) * L2E);
          eg += e; eag += e * gv[r];
        }
        eg += __shfl_xor(eg, 16); eg += __shfl_xor(eg, 32);
        eag += __shfl_xor(eag, 16); eag += __shfl_xor(eag, 32);
        lG = lG * scg + eg; aG = aG * scg + eag; mG = mng;
      }
      asm volatile("s_waitcnt vmcnt(0)" ::: "memory");
      __syncthreads();
    }
  } else {
    // fallback: synchronous reg-staging from f32 x, single buffer
    for (int c = 0; c < NCH; ++c) {
      __syncthreads();
#pragma unroll
      for (int j = 0; j < 8; ++j) {
        int slot = j * 256 + tid;
        int t2 = slot >> 10, s1 = slot & 1023;
        int kk = s1 >> 6, g4 = (s1 >> 4) & 3, row = s1 & 15;
        const float* g = x + ((size_t)(b * NQ + c * 32 + t2 * 16 + row)) * DQ + kk * 32 + g4 * 8;
        *(bf16x8*)(smem + slot * 16) = pack8(*(const float4*)g, *(const float4*)(g + 4));
      }
      __syncthreads();
#pragma unroll
      for (int t2 = 0; t2 < 2; ++t2) {
        f32x4 sU = {0.f, 0.f, 0.f, 0.f}, sG = sU, sF = sU;
        const char* ab = smem + t2 * 16384 + l * 16;
#pragma unroll
        for (int kk = 0; kk < 16; ++kk) {
          bf16x8 a = *(const bf16x8*)(ab + kk * 1024);
          sU = __builtin_amdgcn_mfma_f32_16x16x32_bf16(a, wU[kk], sU, 0, 0, 0);
          sG = __builtin_amdgcn_mfma_f32_16x16x32_bf16(a, wG[kk], sG, 0, 0, 0);
          sF = __builtin_amdgcn_mfma_f32_16x16x32_bf16(a, wF[kk], sF, 0, 0, 0);
        }
        float4 gxv = *(const float4*)(gxb + c * 32 + t2 * 16 + lg4 * 4);
        float pm = fmaxf(fmaxf(sU[0], sU[1]), fmaxf(sU[2], sU[3]));
        pm = fmaxf(pm, __shfl_xor(pm, 16)); pm = fmaxf(pm, __shfl_xor(pm, 32));
        float mn = fmaxf(mU, pm);
        float sc = exp2f((mU - mn) * L2E);
        float es = 0.f, ea = 0.f;
#pragma unroll
        for (int r = 0; r < 4; ++r) {
          float e = exp2f((sU[r] - mn) * L2E);
          es += e; ea += e * sF[r];
        }
        es += __shfl_xor(es, 16); es += __shfl_xor(es, 32);
        ea += __shfl_xor(ea, 16); ea += __shfl_xor(ea, 32);
        lU = lU * sc + es; aU = aU * sc + ea; mU = mn;
        float pg = fmaxf(fmaxf(sG[0], sG[1]), fmaxf(sG[2], sG[3]));
        pg = fmaxf(pg, __shfl_xor(pg, 16)); pg = fmaxf(pg, __shfl_xor(pg, 32));
        float mng = fmaxf(mG, pg);
        float scg = exp2f((mG - mng) * L2E);
        float eg = 0.f, eag = 0.f;
        float gv[4] = {gxv.x, gxv.y, gxv.z, gxv.w};
#pragma unroll
        for (int r = 0; r < 4; ++r) {
          float e = exp2f((sG[r] - mng) * L2E);
          eg += e; eag += e * gv[r];
        }
        eg += __shfl_xor(eg, 16); eg += __shfl_xor(eg, 32);
        eag += __shfl_xor(eag, 16); eag += __shfl_xor(eag, 32);
        lG = lG * scg + eg; aG = aG * scg + eag; mG = mng;
      }
    }
  }

  // ---- epilogue: each wave owns its 16 y fully (no cross-wave merge) ----
  __syncthreads();
  float fOut = aU / lU;
  float gate = tanhf(aG / lG + gate_b[0]);
  int y = ybase + lr;
  float lt = 0.f;
  if (lg4 == 0 && y < YQ) {
    float yv = fOut + fb[y] + yflow[b * YQ + y] * gate;
    out_y[b * YQ + y] = yv;
    float t = target[b * YQ + y];
    lt = fmaxf(yv, 0.f) + log1pf(__expf(-fabsf(yv))) - yv * t;
  }
#pragma unroll
  for (int d = 1; d < 64; d <<= 1) lt += __shfl_xor(lt, d);
  float* ls = (float*)smem;
  if (l == 0) ls[w] = lt;
  __syncthreads();
  if (tid == 0) loss_part[blockIdx.x] = ls[0] + ls[1] + ls[2] + ls[3];
}

__global__ __launch_bounds__(256) void loss_kernel(const float* __restrict__ lp,
                                                   float* __restrict__ out) {
  __shared__ float sb[256];
  float s = 0.f;
  for (int i = threadIdx.x; i < NBLOCKS; i += 256) s += lp[i];
  sb[threadIdx.x] = s;
  __syncthreads();
  for (int st = 128; st > 0; st >>= 1) {
    if (threadIdx.x < st) sb[threadIdx.x] += sb[threadIdx.x + st];
    __syncthreads();
  }
  if (threadIdx.x == 0) out[BQ * YQ] = sb[0] / (float)(BQ * YQ);
}

extern "C" void kernel_launch(void* const* d_in, const int* in_sizes, int n_in,
                              void* d_out, int out_size, void* d_ws, size_t ws_size,
                              hipStream_t stream) {
  const float* x      = (const float*)d_in[0];
  const float* target = (const float*)d_in[1];
  const float* yflow  = (const float*)d_in[2];
  const float* Uw     = (const float*)d_in[3];
  const float* Gw     = (const float*)d_in[4];
  const float* Fw     = (const float*)d_in[5];
  const float* fb     = (const float*)d_in[6];
  const float* gw     = (const float*)d_in[7];
  const float* gb     = (const float*)d_in[8];
  float* out = (float*)d_out;
  char* ws = (char*)d_ws;

  const size_t xbytes = (size_t)BQ * NQ * DQ * 2;        // 16 MB
  const size_t wbytes = (size_t)3 * YQ * DQ * 2;         // ~27.4 MB
  const size_t gxbytes = (size_t)BQ * NQ * 4;            // 32 KB
  const size_t lpbytes = (size_t)NBLOCKS * 4;
  const bool full = ws_size >= xbytes + wbytes + gxbytes + lpbytes;

  char* ws_x; char* ws_w; float* gxp; float* lp;
  if (full) {
    ws_x = ws; ws_w = ws + xbytes;
    gxp = (float*)(ws + xbytes + wbytes);
    lp  = (float*)(ws + xbytes + wbytes + gxbytes);
  } else {
    ws_x = nullptr; ws_w = nullptr;
    gxp = (float*)ws;
    lp  = (float*)(ws + gxbytes);
  }

  (void)hipFuncSetAttribute(reinterpret_cast<const void*>(&fused_kernel<true>),
                            hipFuncAttributeMaxDynamicSharedMemorySize, 65536);
  (void)hipFuncSetAttribute(reinterpret_cast<const void*>(&fused_kernel<false>),
                            hipFuncAttributeMaxDynamicSharedMemorySize, 65536);

  if (full) {
    prep_x<true ><<<dim3(BQ * NQ / 4), 256, 0, stream>>>(x, gw, ws_x, gxp);
    prep_w<<<dim3((3 * YQ + 3) / 4), 256, 0, stream>>>(Uw, Gw, Fw, ws_w);
    fused_kernel<true ><<<dim3(NBLOCKS), 256, 65536, stream>>>(
        x, ws_x, ws_w, Uw, Gw, Fw, gxp, fb, gb, yflow, target, out, lp);
  } else {
    prep_x<false><<<dim3(BQ * NQ / 4), 256, 0, stream>>>(x, gw, ws_x, gxp);
    fused_kernel<false><<<dim3(NBLOCKS), 256, 65536, stream>>>(
        x, ws_x, ws_w, Uw, Gw, Fw, gxp, fb, gb, yflow, target, out, lp);
  }
  loss_kernel<<<1, 256, 0, stream>>>(lp, out);
}

// Round 3
// 279.357 us; speedup vs baseline: 2.1792x; 1.3773x over previous
//
#include <hip/hip_runtime.h>
#include <stdint.h>

#define BQ 4
#define NQ 2048
#define DQ 512
#define YQ 8921
#define YGRP 140                 // y-groups of 64
#define NH 2                     // n halves
#define NCHH 32                  // chunks per half (32 rows each)
#define NUNITS (YGRP * BQ * NH)  // 1120 = 8*140
#define NLP 140                  // merge-kernel blocks
#define L2E 1.44269504088896340736f

typedef __attribute__((ext_vector_type(8))) short bf16x8;
typedef __attribute__((ext_vector_type(4))) float f32x4;

__device__ inline short f2bf(float f) {
  unsigned u = __float_as_uint(f);
  u += 0x7fffu + ((u >> 16) & 1u);   // RTNE
  return (short)(u >> 16);
}

__device__ inline bf16x8 pack8(float4 a, float4 b) {
  bf16x8 h;
  h[0] = f2bf(a.x); h[1] = f2bf(a.y); h[2] = f2bf(a.z); h[3] = f2bf(a.w);
  h[4] = f2bf(b.x); h[5] = f2bf(b.y); h[6] = f2bf(b.z); h[7] = f2bf(b.w);
  return h;
}

__device__ inline void gl_lds16(const void* g, void* l) {
  __builtin_amdgcn_global_load_lds((const __attribute__((address_space(1))) void*)g,
                                   (__attribute__((address_space(3))) void*)l, 16, 0, 0);
}

// ---- combined prep: gx (always), x->bf16 and W->bf16 (FULL only) ----
template<bool FULL>
__global__ __launch_bounds__(256) void prep_all(const float* __restrict__ x,
                                                const float* __restrict__ gate_w,
                                                const float* __restrict__ Uw,
                                                const float* __restrict__ Gw,
                                                const float* __restrict__ Fw,
                                                char* __restrict__ ws_x,
                                                char* __restrict__ ws_w,
                                                float* __restrict__ gx) {
  int lane = threadIdx.x & 63;
  int sub = threadIdx.x >> 6;
  if (blockIdx.x < 2048) {
    int rid = blockIdx.x * 4 + sub;            // b*NQ+n
    const float* src = x + (size_t)rid * DQ + lane * 8;
    float4 v0 = *(const float4*)src;
    float4 v1 = *(const float4*)(src + 4);
    const float* gwp = gate_w + lane * 8;
    float s = v0.x * gwp[0] + v0.y * gwp[1] + v0.z * gwp[2] + v0.w * gwp[3]
            + v1.x * gwp[4] + v1.y * gwp[5] + v1.z * gwp[6] + v1.w * gwp[7];
#pragma unroll
    for (int d = 1; d < 64; d <<= 1) s += __shfl_xor(s, d);
    if (lane == 0) gx[rid] = s;
    if constexpr (FULL)
      *(bf16x8*)(ws_x + (size_t)rid * 1024 + lane * 16) = pack8(v0, v1);
  } else if constexpr (FULL) {
    int rid = (blockIdx.x - 2048) * 4 + sub;   // mat*YQ+y
    if (rid >= 3 * YQ) return;
    int mat = rid / YQ, y = rid % YQ;
    const float* src = (mat == 0 ? Uw : (mat == 1 ? Gw : Fw)) + (size_t)y * DQ + lane * 8;
    float4 v0 = *(const float4*)src;
    float4 v1 = *(const float4*)(src + 4);
    *(bf16x8*)(ws_w + (size_t)rid * 1024 + lane * 16) = pack8(v0, v1);
  }
}

// ---- fused partial: 3 matmuls + per-lane online softmax over one n-half ----
// grid: 1120 (FULL) units = (b, ygrp64, nh); block = 4 waves; wave w: y-tile 16.
// State out: ws_state[(b*NH+nh)][y][6] = {mU,lU,aU,mG,lG,aG}
template<bool FULL>
__global__ __launch_bounds__(256, 2) void fused_kernel(
    const float* __restrict__ x, const char* __restrict__ ws_x,
    const char* __restrict__ ws_w,
    const float* __restrict__ Uw, const float* __restrict__ Gw,
    const float* __restrict__ Fw, const float* __restrict__ gx,
    float* __restrict__ ws_state) {
  extern __shared__ char smem[];
  const int tid = threadIdx.x, l = tid & 63, w = tid >> 6;
  const int lr = l & 15, lg4 = l >> 4;
  // XCD-chunked bijective swizzle: 1120 = 8*140 -> same (b,nh) stays on one XCD
  int u = (blockIdx.x & 7) * (NUNITS / 8) + (blockIdx.x >> 3);
  const int b = u / (YGRP * NH);
  const int r0 = u % (YGRP * NH);
  const int nh = r0 / YGRP, yg = r0 % YGRP;
  const int ybase = yg * 64 + w * 16;
  const int nbase = nh * (NQ / NH);

  // ---- W fragments into registers/AGPRs (48 frags) ----
  bf16x8 wU[16], wG[16], wF[16];
  {
    int y = ybase + lr; if (y >= YQ) y = YQ - 1;
    if constexpr (FULL) {
      const char* p0 = ws_w + ((size_t)y * DQ + lg4 * 8) * 2;
#pragma unroll
      for (int kk = 0; kk < 16; ++kk) {
        wU[kk] = *(const bf16x8*)(p0 + kk * 64);
        wG[kk] = *(const bf16x8*)(p0 + (size_t)YQ * 1024 + kk * 64);
        wF[kk] = *(const bf16x8*)(p0 + (size_t)YQ * 2048 + kk * 64);
      }
    } else {
      const float* pu = Uw + (size_t)y * DQ + lg4 * 8;
      const float* pg = Gw + (size_t)y * DQ + lg4 * 8;
      const float* pf = Fw + (size_t)y * DQ + lg4 * 8;
#pragma unroll
      for (int kk = 0; kk < 16; ++kk) {
        wU[kk] = pack8(*(const float4*)(pu + kk * 32), *(const float4*)(pu + kk * 32 + 4));
        wG[kk] = pack8(*(const float4*)(pg + kk * 32), *(const float4*)(pg + kk * 32 + 4));
        wF[kk] = pack8(*(const float4*)(pf + kk * 32), *(const float4*)(pf + kk * 32 + 4));
      }
    }
  }

  // per-lane independent online-softmax state (disjoint n-subsets)
  float mU = -INFINITY, lU = 0.f, aU = 0.f;
  float mG = -INFINITY, lG = 0.f, aG = 0.f;
  const float* gxb = gx + b * NQ + nbase;

  if constexpr (FULL) {
    const char* xsrc = ws_x + (((size_t)(b * NQ + nbase)) << 10);
    auto stage = [&](int c, int bufi) {
      const char* src = xsrc + ((size_t)c << 15);
      char* lb = smem + bufi * 32768;
#pragma unroll
      for (int j = 0; j < 8; ++j) {
        int s = w * 8 + j;                      // seg = t2*16+kk
        gl_lds16(src + ((((s >> 4) * 16 + lr)) << 10) + (s & 15) * 64 + lg4 * 16,
                 lb + s * 1024);
      }
    };
    stage(0, 0);
    asm volatile("s_waitcnt vmcnt(0)" ::: "memory");
    __syncthreads();

    for (int c = 0; c < NCHH; ++c) {
      if (c + 1 < NCHH) stage(c + 1, (c + 1) & 1);
      const char* buf = smem + (c & 1) * 32768;
#pragma unroll
      for (int t2 = 0; t2 < 2; ++t2) {
        f32x4 sU = {0.f, 0.f, 0.f, 0.f}, sG = sU, sF = sU;
        const char* ab = buf + t2 * 16384 + l * 16;
#pragma unroll
        for (int kk = 0; kk < 16; ++kk) {
          bf16x8 a = *(const bf16x8*)(ab + kk * 1024);
          sU = __builtin_amdgcn_mfma_f32_16x16x32_bf16(a, wU[kk], sU, 0, 0, 0);
          sG = __builtin_amdgcn_mfma_f32_16x16x32_bf16(a, wG[kk], sG, 0, 0, 0);
          sF = __builtin_amdgcn_mfma_f32_16x16x32_bf16(a, wF[kk], sF, 0, 0, 0);
        }
        float4 gxv = *(const float4*)(gxb + c * 32 + t2 * 16 + lg4 * 4);
        float gv[4] = {gxv.x, gxv.y, gxv.z, gxv.w};
        // U branch — lane-local only
        float pm = fmaxf(fmaxf(sU[0], sU[1]), fmaxf(sU[2], sU[3]));
        float mn = fmaxf(mU, pm);
        float sc = exp2f((mU - mn) * L2E);
        float es = 0.f, ea = 0.f;
#pragma unroll
        for (int r = 0; r < 4; ++r) {
          float e = exp2f((sU[r] - mn) * L2E);
          es += e; ea += e * sF[r];
        }
        lU = lU * sc + es; aU = aU * sc + ea; mU = mn;
        // G branch — lane-local only
        float pg = fmaxf(fmaxf(sG[0], sG[1]), fmaxf(sG[2], sG[3]));
        float mng = fmaxf(mG, pg);
        float scg = exp2f((mG - mng) * L2E);
        float eg = 0.f, eag = 0.f;
#pragma unroll
        for (int r = 0; r < 4; ++r) {
          float e = exp2f((sG[r] - mng) * L2E);
          eg += e; eag += e * gv[r];
        }
        lG = lG * scg + eg; aG = aG * scg + eag; mG = mng;
      }
      asm volatile("s_waitcnt vmcnt(0)" ::: "memory");
      __syncthreads();
    }
  } else {
    for (int c = 0; c < NCHH; ++c) {
      __syncthreads();
#pragma unroll
      for (int j = 0; j < 8; ++j) {
        int slot = j * 256 + tid;
        int s = slot >> 6, l2 = slot & 63;
        int row = l2 & 15, g4 = l2 >> 4;
        const float* g = x + ((size_t)(b * NQ + nbase + c * 32 + (s >> 4) * 16 + row)) * DQ
                       + (s & 15) * 32 + g4 * 8;
        *(bf16x8*)(smem + slot * 16) = pack8(*(const float4*)g, *(const float4*)(g + 4));
      }
      __syncthreads();
#pragma unroll
      for (int t2 = 0; t2 < 2; ++t2) {
        f32x4 sU = {0.f, 0.f, 0.f, 0.f}, sG = sU, sF = sU;
        const char* ab = smem + t2 * 16384 + l * 16;
#pragma unroll
        for (int kk = 0; kk < 16; ++kk) {
          bf16x8 a = *(const bf16x8*)(ab + kk * 1024);
          sU = __builtin_amdgcn_mfma_f32_16x16x32_bf16(a, wU[kk], sU, 0, 0, 0);
          sG = __builtin_amdgcn_mfma_f32_16x16x32_bf16(a, wG[kk], sG, 0, 0, 0);
          sF = __builtin_amdgcn_mfma_f32_16x16x32_bf16(a, wF[kk], sF, 0, 0, 0);
        }
        float4 gxv = *(const float4*)(gxb + c * 32 + t2 * 16 + lg4 * 4);
        float gv[4] = {gxv.x, gxv.y, gxv.z, gxv.w};
        float pm = fmaxf(fmaxf(sU[0], sU[1]), fmaxf(sU[2], sU[3]));
        float mn = fmaxf(mU, pm);
        float sc = exp2f((mU - mn) * L2E);
        float es = 0.f, ea = 0.f;
#pragma unroll
        for (int r = 0; r < 4; ++r) {
          float e = exp2f((sU[r] - mn) * L2E);
          es += e; ea += e * sF[r];
        }
        lU = lU * sc + es; aU = aU * sc + ea; mU = mn;
        float pg = fmaxf(fmaxf(sG[0], sG[1]), fmaxf(sG[2], sG[3]));
        float mng = fmaxf(mG, pg);
        float scg = exp2f((mG - mng) * L2E);
        float eg = 0.f, eag = 0.f;
#pragma unroll
        for (int r = 0; r < 4; ++r) {
          float e = exp2f((sG[r] - mng) * L2E);
          eg += e; eag += e * gv[r];
        }
        lG = lG * scg + eg; aG = aG * scg + eag; mG = mng;
      }
    }
  }

  // ---- merge the 4 lane-group states (once, outside the loop) ----
  auto mrg = [&](float& m, float& li, float& ai, int d) {
    float m2 = __shfl_xor(m, d), l2 = __shfl_xor(li, d), a2 = __shfl_xor(ai, d);
    float mm = fmaxf(m, m2);
    float e1 = exp2f((m - mm) * L2E), e2 = exp2f((m2 - mm) * L2E);
    li = li * e1 + l2 * e2; ai = ai * e1 + a2 * e2; m = mm;
  };
  mrg(mU, lU, aU, 16); mrg(mU, lU, aU, 32);
  mrg(mG, lG, aG, 16); mrg(mG, lG, aG, 32);

  int y = ybase + lr;
  if (lg4 == 0 && y < YQ) {
    float* st = ws_state + ((size_t)(b * NH + nh) * YQ + y) * 6;
    st[0] = mU; st[1] = lU; st[2] = aU;
    st[3] = mG; st[4] = lG; st[5] = aG;
  }
}

// ---- merge n-halves + epilogue + per-block loss partials ----
__global__ __launch_bounds__(256) void merge_kernel(
    const float* __restrict__ ws_state, const float* __restrict__ fb,
    const float* __restrict__ gate_b, const float* __restrict__ yflow,
    const float* __restrict__ target, float* __restrict__ out_y,
    float* __restrict__ loss_part) {
  __shared__ float sb[256];
  int t = blockIdx.x * 256 + threadIdx.x;
  float lt = 0.f;
  if (t < BQ * YQ) {
    int b = t / YQ, y = t % YQ;
    const float* s0 = ws_state + ((size_t)(b * NH + 0) * YQ + y) * 6;
    const float* s1 = ws_state + ((size_t)(b * NH + 1) * YQ + y) * 6;
    float mm = fmaxf(s0[0], s1[0]);
    float e0 = exp2f((s0[0] - mm) * L2E), e1 = exp2f((s1[0] - mm) * L2E);
    float fval = (s0[2] * e0 + s1[2] * e1) / (s0[1] * e0 + s1[1] * e1);
    float gm = fmaxf(s0[3], s1[3]);
    float g0 = exp2f((s0[3] - gm) * L2E), g1 = exp2f((s1[3] - gm) * L2E);
    float gate = tanhf((s0[5] * g0 + s1[5] * g1) / (s0[4] * g0 + s1[4] * g1) + gate_b[0]);
    float yv = fval + fb[y] + yflow[t] * gate;
    out_y[t] = yv;
    float tg = target[t];
    lt = fmaxf(yv, 0.f) + log1pf(__expf(-fabsf(yv))) - yv * tg;
  }
  sb[threadIdx.x] = lt;
  __syncthreads();
  for (int st = 128; st > 0; st >>= 1) {
    if (threadIdx.x < st) sb[threadIdx.x] += sb[threadIdx.x + st];
    __syncthreads();
  }
  if (threadIdx.x == 0) loss_part[blockIdx.x] = sb[0];
}

__global__ __launch_bounds__(256) void loss_kernel(const float* __restrict__ lp,
                                                   float* __restrict__ out) {
  __shared__ float sb[256];
  float s = (threadIdx.x < NLP) ? lp[threadIdx.x] : 0.f;
  sb[threadIdx.x] = s;
  __syncthreads();
  for (int st = 128; st > 0; st >>= 1) {
    if (threadIdx.x < st) sb[threadIdx.x] += sb[threadIdx.x + st];
    __syncthreads();
  }
  if (threadIdx.x == 0) out[BQ * YQ] = sb[0] / (float)(BQ * YQ);
}

extern "C" void kernel_launch(void* const* d_in, const int* in_sizes, int n_in,
                              void* d_out, int out_size, void* d_ws, size_t ws_size,
                              hipStream_t stream) {
  const float* x      = (const float*)d_in[0];
  const float* target = (const float*)d_in[1];
  const float* yflow  = (const float*)d_in[2];
  const float* Uw     = (const float*)d_in[3];
  const float* Gw     = (const float*)d_in[4];
  const float* Fw     = (const float*)d_in[5];
  const float* fb     = (const float*)d_in[6];
  const float* gw     = (const float*)d_in[7];
  const float* gb     = (const float*)d_in[8];
  float* out = (float*)d_out;
  char* ws = (char*)d_ws;

  const size_t xbytes  = (size_t)BQ * NQ * DQ * 2;          // 8 MB
  const size_t wbytes  = (size_t)3 * YQ * DQ * 2;           // ~27.4 MB
  const size_t gxbytes = (size_t)BQ * NQ * 4;               // 32 KB
  const size_t stbytes = (size_t)BQ * NH * YQ * 6 * 4;      // ~1.7 MB
  const size_t lpbytes = (size_t)NLP * 4;
  const bool full = ws_size >= xbytes + wbytes + gxbytes + stbytes + lpbytes;

  char* ws_x; char* ws_w; float* gxp; float* stp; float* lp;
  if (full) {
    ws_x = ws; ws_w = ws + xbytes;
    gxp = (float*)(ws + xbytes + wbytes);
    stp = (float*)(ws + xbytes + wbytes + gxbytes);
    lp  = (float*)(ws + xbytes + wbytes + gxbytes + stbytes);
  } else {
    ws_x = nullptr; ws_w = nullptr;
    gxp = (float*)ws;
    stp = (float*)(ws + gxbytes);
    lp  = (float*)(ws + gxbytes + stbytes);
  }

  (void)hipFuncSetAttribute(reinterpret_cast<const void*>(&fused_kernel<true>),
                            hipFuncAttributeMaxDynamicSharedMemorySize, 65536);
  (void)hipFuncSetAttribute(reinterpret_cast<const void*>(&fused_kernel<false>),
                            hipFuncAttributeMaxDynamicSharedMemorySize, 65536);

  if (full) {
    prep_all<true ><<<dim3(2048 + (3 * YQ + 3) / 4), 256, 0, stream>>>(
        x, gw, Uw, Gw, Fw, ws_x, ws_w, gxp);
    fused_kernel<true ><<<dim3(NUNITS), 256, 65536, stream>>>(
        x, ws_x, ws_w, Uw, Gw, Fw, gxp, stp);
  } else {
    prep_all<false><<<dim3(2048), 256, 0, stream>>>(x, gw, Uw, Gw, Fw, ws_x, ws_w, gxp);
    fused_kernel<false><<<dim3(NUNITS), 256, 65536, stream>>>(
        x, ws_x, ws_w, Uw, Gw, Fw, gxp, stp);
  }
  merge_kernel<<<dim3(NLP), 256, 0, stream>>>(stp, fb, gb, yflow, target, out, lp);
  loss_kernel<<<1, 256, 0, stream>>>(lp, out);
}